// Round 1
// baseline (340.368 us; speedup 1.0000x reference)
//
#include <hip/hip_runtime.h>
#include <stdint.h>

// BinaryLinearWscales: out[m,n] = wscale[n] * (x @ sign(W)^T)[m,n] + wbias[n] * rowsum(x)[m]
// M = B*S = 4096, N = DOUT = 4096, K = DIN = 4096.
// Strategy: f16 MFMA GEMM (sign matrix is exactly +-1 in f16), fp32 rank-1 epilogue.

#define MDIM 4096
#define NDIM 4096
#define KDIM 4096

typedef _Float16 half8  __attribute__((ext_vector_type(8)));
typedef _Float16 half4v __attribute__((ext_vector_type(4)));
typedef float    float4v __attribute__((ext_vector_type(4)));

// ---------------- prep: x fp32 -> f16, plus per-row sum (fp32, exact-ish) ----------------
__global__ __launch_bounds__(256) void conv_x_sumx_kernel(
    const float* __restrict__ x, _Float16* __restrict__ xh, float* __restrict__ sumx) {
  const int row = blockIdx.x;
  const float4* xr = (const float4*)(x + (size_t)row * KDIM);
  half4v* xo = (half4v*)(xh + (size_t)row * KDIM);
  float s = 0.f;
#pragma unroll
  for (int u = 0; u < 4; ++u) {
    int c = u * 256 + threadIdx.x;       // float4 index within row (0..1023)
    float4 v = xr[c];
    s += v.x + v.y + v.z + v.w;
    half4v h;
    h[0] = (_Float16)v.x; h[1] = (_Float16)v.y;
    h[2] = (_Float16)v.z; h[3] = (_Float16)v.w;
    xo[c] = h;                           // 8B store
  }
#pragma unroll
  for (int off = 32; off > 0; off >>= 1) s += __shfl_down(s, off, 64);
  __shared__ float red[4];
  if ((threadIdx.x & 63) == 0) red[threadIdx.x >> 6] = s;
  __syncthreads();
  if (threadIdx.x == 0) sumx[row] = red[0] + red[1] + red[2] + red[3];
}

// ---------------- prep: weight fp32 -> sign in f16 (+1/-1/0) ----------------
__global__ __launch_bounds__(256) void conv_w_sign_kernel(
    const float* __restrict__ w, _Float16* __restrict__ wsg) {
  size_t i = (size_t)blockIdx.x * 256 + threadIdx.x;   // float4 index
  float4 v = ((const float4*)w)[i];
  half4v h;
  h[0] = v.x > 0.f ? (_Float16)1.f : (v.x < 0.f ? (_Float16)-1.f : (_Float16)0.f);
  h[1] = v.y > 0.f ? (_Float16)1.f : (v.y < 0.f ? (_Float16)-1.f : (_Float16)0.f);
  h[2] = v.z > 0.f ? (_Float16)1.f : (v.z < 0.f ? (_Float16)-1.f : (_Float16)0.f);
  h[3] = v.w > 0.f ? (_Float16)1.f : (v.w < 0.f ? (_Float16)-1.f : (_Float16)0.f);
  ((half4v*)wsg)[i] = h;
}

// ---------------- main GEMM: C = A (MxK) * Bs^T (Bs is NxK, K-contiguous) ----------------
// 128x128 tile, BK=32, 256 threads = 4 waves in 2x2, each wave 64x64 via 4x4 frags of
// 16x16x32 f16 MFMA. Staging via global_load_lds width=16. XOR swizzle on 16B blocks:
//   cb_phys = cb_log ^ ((row>>1)&3)  -> ds_read_b128 hits 8 distinct 16B bank-groups / 8 rows.
__global__ __launch_bounds__(256) void gemm_bin_kernel(
    const _Float16* __restrict__ A,   // [M,K] f16
    const _Float16* __restrict__ Bs,  // [N,K] f16 (sign matrix)
    const float* __restrict__ wscale, const float* __restrict__ wbias,
    const float* __restrict__ sumx, float* __restrict__ C) {
  __shared__ __align__(16) _Float16 sA[128 * 32];  // 8 KB
  __shared__ __align__(16) _Float16 sB[128 * 32];  // 8 KB

  const int bn = blockIdx.x & 31;
  const int bm = blockIdx.x >> 5;
  const int tm0 = bm * 128, tn0 = bn * 128;
  const int tid = threadIdx.x;
  const int lane = tid & 63, wave = tid >> 6;
  const int quad = lane >> 4, l16 = lane & 15;
  const int wmo = (wave >> 1) * 64, wno = (wave & 1) * 64;

  float4v acc[4][4];
  const float4v zero4 = {0.f, 0.f, 0.f, 0.f};
#pragma unroll
  for (int i = 0; i < 4; ++i)
#pragma unroll
    for (int j = 0; j < 4; ++j) acc[i][j] = zero4;

  // staging geometry (loop-invariant parts): chunk c = wave*2+q covers LDS rows [c*16, c*16+16)
  // lane covers row = c*16 + lane/4, phys 16B-block cb_phys = lane&3 (LDS = base + lane*16)
  int s_row[2], s_cbl[2];
#pragma unroll
  for (int q = 0; q < 2; ++q) {
    int c = wave * 2 + q;
    int row = c * 16 + (lane >> 2);
    int cbp = lane & 3;
    s_row[q] = row;
    s_cbl[q] = cbp ^ ((row >> 1) & 3);   // logical 16B block read from global
  }

  // fragment-read LDS addresses (loop-invariant)
  const _Float16* aRd[4];
  const _Float16* bRd[4];
#pragma unroll
  for (int i = 0; i < 4; ++i) {
    int row = wmo + i * 16 + l16;
    int cbp = quad ^ ((row >> 1) & 3);
    aRd[i] = sA + row * 32 + cbp * 8;
  }
#pragma unroll
  for (int j = 0; j < 4; ++j) {
    int row = wno + j * 16 + l16;
    int cbp = quad ^ ((row >> 1) & 3);
    bRd[j] = sB + row * 32 + cbp * 8;
  }

  for (int kt = 0; kt < KDIM; kt += 32) {
#pragma unroll
    for (int q = 0; q < 2; ++q) {
      int c = wave * 2 + q;
      const _Float16* ga = A  + (size_t)(tm0 + s_row[q]) * KDIM + kt + s_cbl[q] * 8;
      const _Float16* gb = Bs + (size_t)(tn0 + s_row[q]) * KDIM + kt + s_cbl[q] * 8;
      _Float16* la = sA + c * 512 + lane * 8;
      _Float16* lb = sB + c * 512 + lane * 8;
      __builtin_amdgcn_global_load_lds(
          (const __attribute__((address_space(1))) void*)ga,
          (__attribute__((address_space(3))) void*)la, 16, 0, 0);
      __builtin_amdgcn_global_load_lds(
          (const __attribute__((address_space(1))) void*)gb,
          (__attribute__((address_space(3))) void*)lb, 16, 0, 0);
    }
    __syncthreads();

    half8 af[4], bfr[4];
#pragma unroll
    for (int i = 0; i < 4; ++i) af[i] = *(const half8*)aRd[i];
#pragma unroll
    for (int j = 0; j < 4; ++j) bfr[j] = *(const half8*)bRd[j];

#pragma unroll
    for (int i = 0; i < 4; ++i)
#pragma unroll
      for (int j = 0; j < 4; ++j)
        acc[i][j] = __builtin_amdgcn_mfma_f32_16x16x32_f16(af[i], bfr[j], acc[i][j], 0, 0, 0);

    __syncthreads();
  }

  // epilogue: C[m,n] = wscale[n]*acc + wbias[n]*sumx[m]
  float wsv[4], wbv[4];
#pragma unroll
  for (int j = 0; j < 4; ++j) {
    int n = tn0 + wno + j * 16 + l16;
    wsv[j] = wscale[n];
    wbv[j] = wbias[n];
  }
#pragma unroll
  for (int i = 0; i < 4; ++i) {
#pragma unroll
    for (int r = 0; r < 4; ++r) {
      int m = tm0 + wmo + i * 16 + quad * 4 + r;   // C/D layout: row = quad*4 + reg
      float sx = sumx[m];
      float* crow = C + (size_t)m * NDIM + tn0 + wno + l16;  // col = lane&15
#pragma unroll
      for (int j = 0; j < 4; ++j) {
        crow[j * 16] = wsv[j] * acc[i][j][r] + wbv[j] * sx;
      }
    }
  }
}

extern "C" void kernel_launch(void* const* d_in, const int* in_sizes, int n_in,
                              void* d_out, int out_size, void* d_ws, size_t ws_size,
                              hipStream_t stream) {
  const float* x      = (const float*)d_in[0];
  const float* weight = (const float*)d_in[1];
  const float* wscale = (const float*)d_in[2];
  const float* wbias  = (const float*)d_in[3];
  float* out = (float*)d_out;

  // workspace layout: [0,32MB) x in f16; [32MB,64MB) sign(W) in f16; [64MB,+16KB) sumx fp32
  _Float16* xh  = (_Float16*)d_ws;
  _Float16* wsg = xh + (size_t)MDIM * KDIM;
  float* sumx   = (float*)(wsg + (size_t)NDIM * KDIM);

  conv_x_sumx_kernel<<<MDIM, 256, 0, stream>>>(x, xh, sumx);
  conv_w_sign_kernel<<<((size_t)NDIM * KDIM) / (4 * 256), 256, 0, stream>>>(weight, wsg);
  gemm_bin_kernel<<<(MDIM / 128) * (NDIM / 128), 256, 0, stream>>>(xh, wsg, wscale, wbias, sumx, out);
}

// Round 2
// 250.370 us; speedup vs baseline: 1.3595x; 1.3595x over previous
//
#include <hip/hip_runtime.h>
#include <stdint.h>

// BinaryLinearWscales: out[m,n] = wscale[n] * (x @ sign(W)^T)[m,n] + wbias[n] * rowsum(x)[m]
// M = B*S = 4096, N = DOUT = 4096, K = DIN = 4096.
// Round 2: i8 MFMA (sign matrix is exactly +-1 in i8; x quantized per-row to i8,
// i32 accumulate exact, fp32 epilogue rescale). i8 MFMA = 2x f16 rate.

#define MDIM 4096
#define NDIM 4096
#define KDIM 4096

typedef int   int4v  __attribute__((ext_vector_type(4)));
typedef float float4v __attribute__((ext_vector_type(4)));

__device__ __forceinline__ int pack4_rn(float a, float b, float c, float d, float inv) {
  int ia = __float2int_rn(a * inv) & 0xff;
  int ib = __float2int_rn(b * inv) & 0xff;
  int ic = __float2int_rn(c * inv) & 0xff;
  int id = __float2int_rn(d * inv) & 0xff;
  return ia | (ib << 8) | (ic << 16) | (id << 24);
}

__device__ __forceinline__ int sgn8(float v) {
  return (v > 0.f) ? 1 : ((v < 0.f) ? 0xff : 0);
}

// ---------------- prep: x fp32 -> i8 per-row symmetric quant + rowsum + rowscale ----------
__global__ __launch_bounds__(256) void quant_x_kernel(
    const float* __restrict__ x, char* __restrict__ xq,
    float* __restrict__ xscale, float* __restrict__ sumx) {
  const int row = blockIdx.x;
  const int tid = threadIdx.x;
  const float4* xr = (const float4*)(x + (size_t)row * KDIM);
  float4 v[4];
  float s = 0.f, amax = 0.f;
#pragma unroll
  for (int u = 0; u < 4; ++u) {
    v[u] = xr[tid * 4 + u];   // thread owns 16 contiguous floats
    s += v[u].x + v[u].y + v[u].z + v[u].w;
    amax = fmaxf(amax, fmaxf(fmaxf(fabsf(v[u].x), fabsf(v[u].y)),
                             fmaxf(fabsf(v[u].z), fabsf(v[u].w))));
  }
#pragma unroll
  for (int off = 32; off > 0; off >>= 1) {
    s += __shfl_down(s, off, 64);
    amax = fmaxf(amax, __shfl_down(amax, off, 64));
  }
  __shared__ float rs[4], rm[4], bcast;
  if ((tid & 63) == 0) { rs[tid >> 6] = s; rm[tid >> 6] = amax; }
  __syncthreads();
  if (tid == 0) {
    sumx[row] = rs[0] + rs[1] + rs[2] + rs[3];
    float mt = fmaxf(fmaxf(rm[0], rm[1]), fmaxf(rm[2], rm[3]));
    xscale[row] = mt * (1.f / 127.f);
    bcast = (mt > 0.f) ? 127.f / mt : 0.f;
  }
  __syncthreads();
  const float inv = bcast;
  int4v o;
#pragma unroll
  for (int u = 0; u < 4; ++u)
    o[u] = pack4_rn(v[u].x, v[u].y, v[u].z, v[u].w, inv);
  ((int4v*)(xq + (size_t)row * KDIM))[tid] = o;   // 16B coalesced
}

// ---------------- prep: weight fp32 -> sign in i8 (+1/-1/0) ----------------
__global__ __launch_bounds__(256) void sign_w_kernel(
    const float* __restrict__ w, char* __restrict__ wsg) {
  const size_t e0 = ((size_t)blockIdx.x * 256 + threadIdx.x) * 16;  // element base
  const float4* wr = (const float4*)(w + e0);
  int4v o;
#pragma unroll
  for (int u = 0; u < 4; ++u) {
    float4 v = wr[u];
    o[u] = sgn8(v.x) | (sgn8(v.y) << 8) | (sgn8(v.z) << 16) | (sgn8(v.w) << 24);
  }
  *((int4v*)(wsg + e0)) = o;
}

// ---------------- main GEMM: C = A (MxK i8) * Bs^T (Bs is NxK i8) ----------------
// 128x128 tile, BK=64, 256 threads = 4 waves (2x2), each wave 64x64 via 4x4 frags of
// mfma_i32_16x16x64_i8. Staging: global_load_lds width=16, rows = 64B (4 x 16B blocks).
// XOR swizzle pblk = lblk ^ ((row>>1)&3): quad's 16 lanes spread over all 8
// (row-parity x block) bank regions -> 2 lanes/region = free (m136).
__global__ __launch_bounds__(256) void gemm_bin_i8_kernel(
    const char* __restrict__ A,   // [M,K] i8 quantized x
    const char* __restrict__ Bs,  // [N,K] i8 sign matrix
    const float* __restrict__ wscale, const float* __restrict__ wbias,
    const float* __restrict__ xscale, const float* __restrict__ sumx,
    float* __restrict__ C) {
  __shared__ __align__(16) char sA[128 * 64];  // 8 KB
  __shared__ __align__(16) char sB[128 * 64];  // 8 KB

  const int bn = blockIdx.x & 31;
  const int bm = blockIdx.x >> 5;
  const int tm0 = bm * 128, tn0 = bn * 128;
  const int tid = threadIdx.x;
  const int lane = tid & 63, wave = tid >> 6;
  const int quad = lane >> 4, l16 = lane & 15;
  const int wmo = (wave >> 1) * 64, wno = (wave & 1) * 64;

  int4v acc[4][4];
  const int4v zero4 = {0, 0, 0, 0};
#pragma unroll
  for (int i = 0; i < 4; ++i)
#pragma unroll
    for (int j = 0; j < 4; ++j) acc[i][j] = zero4;

  // staging geometry: 16B unit p = q*256 + tid; row = p>>2, phys blk = p&3,
  // logical (global) blk = pblk ^ ((row>>1)&3)
  int st_row[2], st_lblk[2];
#pragma unroll
  for (int q = 0; q < 2; ++q) {
    int p = q * 256 + tid;
    int row = p >> 2, pblk = p & 3;
    st_row[q] = row;
    st_lblk[q] = pblk ^ ((row >> 1) & 3);
  }

  // fragment-read LDS addresses (loop-invariant)
  const char* aRd[4];
  const char* bRd[4];
#pragma unroll
  for (int i = 0; i < 4; ++i) {
    int row = wmo + i * 16 + l16;
    aRd[i] = sA + row * 64 + (quad ^ ((row >> 1) & 3)) * 16;
  }
#pragma unroll
  for (int j = 0; j < 4; ++j) {
    int row = wno + j * 16 + l16;
    bRd[j] = sB + row * 64 + (quad ^ ((row >> 1) & 3)) * 16;
  }

  for (int kt = 0; kt < KDIM; kt += 64) {
#pragma unroll
    for (int q = 0; q < 2; ++q) {
      const char* ga = A  + (size_t)(tm0 + st_row[q]) * KDIM + kt + st_lblk[q] * 16;
      const char* gb = Bs + (size_t)(tn0 + st_row[q]) * KDIM + kt + st_lblk[q] * 16;
      char* la = sA + (q * 256 + tid) * 16;
      char* lb = sB + (q * 256 + tid) * 16;
      __builtin_amdgcn_global_load_lds(
          (const __attribute__((address_space(1))) void*)ga,
          (__attribute__((address_space(3))) void*)la, 16, 0, 0);
      __builtin_amdgcn_global_load_lds(
          (const __attribute__((address_space(1))) void*)gb,
          (__attribute__((address_space(3))) void*)lb, 16, 0, 0);
    }
    __syncthreads();

    int4v af[4], bfr[4];
#pragma unroll
    for (int i = 0; i < 4; ++i) af[i] = *(const int4v*)aRd[i];
#pragma unroll
    for (int j = 0; j < 4; ++j) bfr[j] = *(const int4v*)bRd[j];

#pragma unroll
    for (int i = 0; i < 4; ++i)
#pragma unroll
      for (int j = 0; j < 4; ++j)
        acc[i][j] = __builtin_amdgcn_mfma_i32_16x16x64_i8(af[i], bfr[j], acc[i][j], 0, 0, 0);

    __syncthreads();
  }

  // epilogue: C[m,n] = wscale[n]*xscale[m]*acc + wbias[n]*sumx[m]
  float wsv[4], wbv[4];
#pragma unroll
  for (int j = 0; j < 4; ++j) {
    int n = tn0 + wno + j * 16 + l16;
    wsv[j] = wscale[n];
    wbv[j] = wbias[n];
  }
#pragma unroll
  for (int i = 0; i < 4; ++i) {
#pragma unroll
    for (int r = 0; r < 4; ++r) {
      int m = tm0 + wmo + i * 16 + quad * 4 + r;   // C/D layout: row = quad*4 + reg
      float xs = xscale[m];
      float sx = sumx[m];
      float* crow = C + (size_t)m * NDIM + tn0 + wno + l16;  // col = lane&15
#pragma unroll
      for (int j = 0; j < 4; ++j) {
        crow[j * 16] = wsv[j] * xs * (float)acc[i][j][r] + wbv[j] * sx;
      }
    }
  }
}

extern "C" void kernel_launch(void* const* d_in, const int* in_sizes, int n_in,
                              void* d_out, int out_size, void* d_ws, size_t ws_size,
                              hipStream_t stream) {
  const float* x      = (const float*)d_in[0];
  const float* weight = (const float*)d_in[1];
  const float* wscale = (const float*)d_in[2];
  const float* wbias  = (const float*)d_in[3];
  float* out = (float*)d_out;

  // workspace: [0,16MB) xq i8; [16,32MB) sign(W) i8; then xscale, sumx fp32 (16KB each)
  char* xq  = (char*)d_ws;
  char* wsg = xq + (size_t)MDIM * KDIM;
  float* xscale = (float*)(wsg + (size_t)NDIM * KDIM);
  float* sumx   = xscale + MDIM;

  quant_x_kernel<<<MDIM, 256, 0, stream>>>(x, xq, xscale, sumx);
  sign_w_kernel<<<((size_t)NDIM * KDIM) / (16 * 256), 256, 0, stream>>>(weight, wsg);
  gemm_bin_i8_kernel<<<(MDIM / 128) * (NDIM / 128), 256, 0, stream>>>(
      xq, wsg, wscale, wbias, xscale, sumx, out);
}

// Round 3
// 247.437 us; speedup vs baseline: 1.3756x; 1.0119x over previous
//
#include <hip/hip_runtime.h>
#include <stdint.h>

// BinaryLinearWscales: out[m,n] = wscale[n] * (x @ sign(W)^T)[m,n] + wbias[n] * rowsum(x)[m]
// M = B*S = 4096, N = DOUT = 4096, K = DIN = 4096.
// Round 3: i8 MFMA, BK=128 (32 MFMA per barrier pair, 32 KB LDS), XOR-8 swizzle,
// fully-coalesced prep kernels.

#define MDIM 4096
#define NDIM 4096
#define KDIM 4096

typedef int   int4v  __attribute__((ext_vector_type(4)));

__device__ __forceinline__ int pack4_rn(float a, float b, float c, float d, float inv) {
  int ia = __float2int_rn(a * inv) & 0xff;
  int ib = __float2int_rn(b * inv) & 0xff;
  int ic = __float2int_rn(c * inv) & 0xff;
  int id = __float2int_rn(d * inv) & 0xff;
  return ia | (ib << 8) | (ic << 16) | (id << 24);
}

__device__ __forceinline__ int sgn8(float v) {
  return (v > 0.f) ? 1 : ((v < 0.f) ? 0xff : 0);
}

// ---------------- prep: x fp32 -> i8 per-row symmetric quant + rowsum + rowscale ----------
// One block per row. Coalesced float4 loads (lane-contiguous), coalesced 4B int stores.
__global__ __launch_bounds__(256) void quant_x_kernel(
    const float* __restrict__ x, char* __restrict__ xq,
    float* __restrict__ xscale, float* __restrict__ sumx) {
  const int row = blockIdx.x;
  const int tid = threadIdx.x;
  const float4* xr = (const float4*)(x + (size_t)row * KDIM);
  float4 v[4];
  float s = 0.f, amax = 0.f;
#pragma unroll
  for (int u = 0; u < 4; ++u) {
    v[u] = xr[u * 256 + tid];            // lane-contiguous 16B loads
    s += v[u].x + v[u].y + v[u].z + v[u].w;
    amax = fmaxf(amax, fmaxf(fmaxf(fabsf(v[u].x), fabsf(v[u].y)),
                             fmaxf(fabsf(v[u].z), fabsf(v[u].w))));
  }
#pragma unroll
  for (int off = 32; off > 0; off >>= 1) {
    s += __shfl_down(s, off, 64);
    amax = fmaxf(amax, __shfl_down(amax, off, 64));
  }
  __shared__ float rs[4], rm[4], bcast;
  if ((tid & 63) == 0) { rs[tid >> 6] = s; rm[tid >> 6] = amax; }
  __syncthreads();
  if (tid == 0) {
    sumx[row] = rs[0] + rs[1] + rs[2] + rs[3];
    float mt = fmaxf(fmaxf(rm[0], rm[1]), fmaxf(rm[2], rm[3]));
    xscale[row] = mt * (1.f / 127.f);
    bcast = (mt > 0.f) ? 127.f / mt : 0.f;
  }
  __syncthreads();
  const float inv = bcast;
  int* xo = (int*)(xq + (size_t)row * KDIM);
#pragma unroll
  for (int u = 0; u < 4; ++u)
    xo[u * 256 + tid] = pack4_rn(v[u].x, v[u].y, v[u].z, v[u].w, inv);  // coalesced 4B
}

// ---------------- prep: weight fp32 -> sign in i8 (+1/-1/0), streaming coalesced ----------
__global__ __launch_bounds__(256) void sign_w_kernel(
    const float* __restrict__ w, char* __restrict__ wsg) {
  const size_t base = (size_t)blockIdx.x * (256 * 4);
  const float4* wr = (const float4*)w;
  int* wo = (int*)wsg;
#pragma unroll
  for (int u = 0; u < 4; ++u) {
    size_t i = base + u * 256 + threadIdx.x;     // float4 index, lane-contiguous
    float4 v = wr[i];
    wo[i] = sgn8(v.x) | (sgn8(v.y) << 8) | (sgn8(v.z) << 16) | (sgn8(v.w) << 24);
  }
}

// ---------------- main GEMM: C = A (MxK i8) * Bs^T (Bs is NxK i8) ----------------
// 128x128 tile, BK=128, 256 threads = 4 waves (2x2), each wave 64x64 via 4x4 frags of
// mfma_i32_16x16x64_i8, 2 k-steps per K-iter (32 MFMA / barrier pair).
// Rows are 128B = 8 x 16B blocks. Swizzle: phys_blk = logical_blk ^ (row & 7).
// Bank group = phys_blk*4..+3; a quad's 16 lanes have (row&7) covering 0..7 twice ->
// 2 lanes per bank group = conflict-free (m136).
__global__ __launch_bounds__(256) void gemm_bin_i8_kernel(
    const char* __restrict__ A,   // [M,K] i8 quantized x
    const char* __restrict__ Bs,  // [N,K] i8 sign matrix
    const float* __restrict__ wscale, const float* __restrict__ wbias,
    const float* __restrict__ xscale, const float* __restrict__ sumx,
    float* __restrict__ C) {
  __shared__ __align__(16) char sA[128 * 128];  // 16 KB
  __shared__ __align__(16) char sB[128 * 128];  // 16 KB

  const int bn = blockIdx.x & 31;
  const int bm = blockIdx.x >> 5;
  const int tm0 = bm * 128, tn0 = bn * 128;
  const int tid = threadIdx.x;
  const int lane = tid & 63, wave = tid >> 6;
  const int quad = lane >> 4, l16 = lane & 15;
  const int wmo = (wave >> 1) * 64, wno = (wave & 1) * 64;

  int4v acc[4][4];
  const int4v zero4 = {0, 0, 0, 0};
#pragma unroll
  for (int i = 0; i < 4; ++i)
#pragma unroll
    for (int j = 0; j < 4; ++j) acc[i][j] = zero4;

  // staging geometry: 16B unit u = q*256 + tid (q=0..3); LDS dst = u*16 (linear);
  // row = u>>3, pblk = u&7, logical blk read from global = pblk ^ (row&7)
  int st_row[4], st_lblk[4];
#pragma unroll
  for (int q = 0; q < 4; ++q) {
    int u = q * 256 + tid;
    int row = u >> 3, pblk = u & 7;
    st_row[q] = row;
    st_lblk[q] = pblk ^ (row & 7);
  }

  // fragment-read LDS offsets: frag row r, k-step s -> 16B block b = s*4 + quad,
  // phys = b ^ (r&7), addr = r*128 + phys*16
  int aOff[4][2], bOff[4][2];
#pragma unroll
  for (int i = 0; i < 4; ++i) {
    int r = wmo + i * 16 + l16;
#pragma unroll
    for (int s = 0; s < 2; ++s)
      aOff[i][s] = r * 128 + ((s * 4 + quad) ^ (r & 7)) * 16;
  }
#pragma unroll
  for (int j = 0; j < 4; ++j) {
    int r = wno + j * 16 + l16;
#pragma unroll
    for (int s = 0; s < 2; ++s)
      bOff[j][s] = r * 128 + ((s * 4 + quad) ^ (r & 7)) * 16;
  }

  for (int kt = 0; kt < KDIM; kt += 128) {
#pragma unroll
    for (int q = 0; q < 4; ++q) {
      const char* ga = A  + (size_t)(tm0 + st_row[q]) * KDIM + kt + st_lblk[q] * 16;
      const char* gb = Bs + (size_t)(tn0 + st_row[q]) * KDIM + kt + st_lblk[q] * 16;
      char* la = sA + (q * 256 + tid) * 16;
      char* lb = sB + (q * 256 + tid) * 16;
      __builtin_amdgcn_global_load_lds(
          (const __attribute__((address_space(1))) void*)ga,
          (__attribute__((address_space(3))) void*)la, 16, 0, 0);
      __builtin_amdgcn_global_load_lds(
          (const __attribute__((address_space(1))) void*)gb,
          (__attribute__((address_space(3))) void*)lb, 16, 0, 0);
    }
    __syncthreads();

#pragma unroll
    for (int s = 0; s < 2; ++s) {
      int4v af[4], bfr[4];
#pragma unroll
      for (int i = 0; i < 4; ++i) af[i] = *(const int4v*)(sA + aOff[i][s]);
#pragma unroll
      for (int j = 0; j < 4; ++j) bfr[j] = *(const int4v*)(sB + bOff[j][s]);
#pragma unroll
      for (int i = 0; i < 4; ++i)
#pragma unroll
        for (int j = 0; j < 4; ++j)
          acc[i][j] = __builtin_amdgcn_mfma_i32_16x16x64_i8(af[i], bfr[j], acc[i][j], 0, 0, 0);
    }

    __syncthreads();
  }

  // epilogue: C[m,n] = wscale[n]*xscale[m]*acc + wbias[n]*sumx[m]
  float wsv[4], wbv[4];
#pragma unroll
  for (int j = 0; j < 4; ++j) {
    int n = tn0 + wno + j * 16 + l16;
    wsv[j] = wscale[n];
    wbv[j] = wbias[n];
  }
#pragma unroll
  for (int i = 0; i < 4; ++i) {
#pragma unroll
    for (int r = 0; r < 4; ++r) {
      int m = tm0 + wmo + i * 16 + quad * 4 + r;   // C/D layout: row = quad*4 + reg
      float xs = xscale[m];
      float sx = sumx[m];
      float* crow = C + (size_t)m * NDIM + tn0 + wno + l16;  // col = lane&15
#pragma unroll
      for (int j = 0; j < 4; ++j) {
        crow[j * 16] = wsv[j] * xs * (float)acc[i][j][r] + wbv[j] * sx;
      }
    }
  }
}

extern "C" void kernel_launch(void* const* d_in, const int* in_sizes, int n_in,
                              void* d_out, int out_size, void* d_ws, size_t ws_size,
                              hipStream_t stream) {
  const float* x      = (const float*)d_in[0];
  const float* weight = (const float*)d_in[1];
  const float* wscale = (const float*)d_in[2];
  const float* wbias  = (const float*)d_in[3];
  float* out = (float*)d_out;

  // workspace: [0,16MB) xq i8; [16,32MB) sign(W) i8; then xscale, sumx fp32 (16KB each)
  char* xq  = (char*)d_ws;
  char* wsg = xq + (size_t)MDIM * KDIM;
  float* xscale = (float*)(wsg + (size_t)NDIM * KDIM);
  float* sumx   = xscale + MDIM;

  quant_x_kernel<<<MDIM, 256, 0, stream>>>(x, xq, xscale, sumx);
  sign_w_kernel<<<((size_t)NDIM * KDIM) / (16 * 256), 256, 0, stream>>>(weight, wsg);
  gemm_bin_i8_kernel<<<(MDIM / 128) * (NDIM / 128), 256, 0, stream>>>(
      xq, wsg, wscale, wbias, xscale, sumx, out);
}